// Round 2
// 816.448 us; speedup vs baseline: 1.0139x; 1.0139x over previous
//
#include <hip/hip_runtime.h>
#include <hip/hip_bf16.h>

// out[b,k,o,f] = entmax15( x[b,f,:] @ W2'[k,:,o] ) * values[k,o,f]
// W2'[k,x,o] = 0.0625 * sum_y bw[k,x,y] * q[k,o,y]   (scale * (alpha-1) folded in)
// b=2048, k=8, o=64, f=128, x=128, y=64

using half8_t  = __attribute__((ext_vector_type(8))) _Float16;
using half4_t  = __attribute__((ext_vector_type(4))) _Float16;
using fp16x2   = __attribute__((ext_vector_type(2))) __fp16;   // builtin-compatible
using floatx4  = __attribute__((ext_vector_type(4))) float;

#define NBIS 8    // fp16 bisection iters -> bracket width 0.91*2^-8*2 = 7.1e-3

#if defined(__has_builtin)
#if __has_builtin(__builtin_amdgcn_fdot2)
#define HAS_FDOT2 1
#endif
#endif
#ifndef HAS_FDOT2
#define HAS_FDOT2 0
#endif

__device__ __forceinline__ float frcp(float x) {
#if __has_builtin(__builtin_amdgcn_rcpf)
    return __builtin_amdgcn_rcpf(x);   // 1-ulp rcp; plenty for Newton step sizing
#else
    return 1.0f / x;
#endif
}

// ---------------- Kernel A: W2'[k][o][x] fp16 into workspace ----------------
__global__ __launch_bounds__(256) void w2_kernel(const float* __restrict__ bw,
                                                 const float* __restrict__ qm,
                                                 _Float16* __restrict__ W2h) {
    const int k  = blockIdx.x >> 3;
    const int og = blockIdx.x & 7;          // o-chunk of 8 rows
    __shared__ float Lbw[128 * 65];         // [x][y] padded (+1) -> conflict-free
    __shared__ float Lq[8 * 64];            // [o][y]
    const int t = threadIdx.x;

    const float* bwk = bw + k * 8192;       // [128][64]
    #pragma unroll
    for (int i2 = 0; i2 < 8; ++i2) {
        int i = t + i2 * 256;               // float4 index, 2048 total
        float4 v = ((const float4*)bwk)[i];
        int xx = (i * 4) >> 6, y = (i * 4) & 63;
        float* dst = &Lbw[xx * 65 + y];
        dst[0] = v.x; dst[1] = v.y; dst[2] = v.z; dst[3] = v.w;
    }
    const float* qk = qm + k * 4096 + og * 8 * 64;
    if (t < 128) ((float4*)Lq)[t] = ((const float4*)qk)[t];
    __syncthreads();

    #pragma unroll
    for (int i = 0; i < 4; ++i) {
        int ox = i * 256 + t;               // 1024 outputs: [8 o][128 x]
        int o = ox >> 7, x = ox & 127;
        const float* brow = &Lbw[x * 65];
        const float* qrow = &Lq[o * 64];
        float acc = 0.f;
        #pragma unroll
        for (int y = 0; y < 64; ++y) acc = fmaf(brow[y], qrow[y], acc);
        W2h[(k * 64 + og * 8 + o) * 128 + x] = (_Float16)(acc * 0.0625f);
    }
}

// ---------------- Kernel B: fused GEMM + entmax + scale ----------------
// block = one (b,k); 256 threads = 4 waves; wave w owns o in [16w,16w+16)
__global__ __launch_bounds__(256, 3) void satt_kernel(
        const float* __restrict__ xg, const _Float16* __restrict__ W2h,
        const float* __restrict__ values, float* __restrict__ out) {
    // XCD-local remap: bid%8 == b%8, so all 8 k-blocks of one b hit the SAME
    // per-XCD L2 (64 bids apart) -> x[b] fetched from HBM once, not 4x.
    const int bid = blockIdx.x;
    const int k = (bid & 511) >> 6;
    const int b = ((bid >> 9) << 6) | (bid & 63);
    const int t = threadIdx.x;
    const int w = t >> 6, l = t & 63;

    // union: {Ash[64][136] fp16 (17408B) + Bsh[128][136] fp16 (34816B)} / zsh[64][132] f32 (33792B)
    __shared__ __align__(16) char smem[52224];
    _Float16* Ash = (_Float16*)smem;
    _Float16* Bsh = (_Float16*)(smem + 17408);
    float*    zsh = (float*)smem;

    // Stage A: W2'[k] = [64 o][128 x] fp16 (16 KB), 1024 x 16B chunks
    const _Float16* w2k = W2h + k * 8192;
    #pragma unroll
    for (int j = 0; j < 4; ++j) {
        int c = t + 256 * j;
        int o = c >> 4, x0 = (c & 15) * 8;
        uint4 v = ((const uint4*)w2k)[c];
        *(uint4*)(Ash + o * 136 + x0) = v;
    }
    // Stage B: x[b] = [128 f][128 x] fp32 -> fp16 LDS
    const float* xb = xg + (size_t)b * 16384;
    #pragma unroll
    for (int j = 0; j < 16; ++j) {
        int c = t + 256 * j;                // float4 index, 4096 total
        int f = c >> 5, x0 = (c & 31) * 4;
        float4 v = ((const float4*)xb)[c];
        half4_t h;
        h[0] = (_Float16)v.x; h[1] = (_Float16)v.y;
        h[2] = (_Float16)v.z; h[3] = (_Float16)v.w;
        *(half4_t*)(Bsh + f * 136 + x0) = h;
    }
    __syncthreads();

    // MFMA: z[o,f] = A[o,x] * B[x,f];  A-frag: m=l&15, k=(l>>4)*8+j ; B-frag: n=l&15
    const int q = l >> 4, c16 = l & 15;
    half8_t afrag[4];
    #pragma unroll
    for (int kk = 0; kk < 4; ++kk)
        afrag[kk] = *(const half8_t*)(Ash + (w * 16 + c16) * 136 + kk * 32 + q * 8);

    floatx4 acc[8];
    #pragma unroll
    for (int ft = 0; ft < 8; ++ft) acc[ft] = (floatx4){0.f, 0.f, 0.f, 0.f};

    #pragma unroll
    for (int kk = 0; kk < 4; ++kk) {
        #pragma unroll
        for (int ft = 0; ft < 8; ++ft) {
            half8_t bfrag = *(const half8_t*)(Bsh + (ft * 16 + c16) * 136 + kk * 32 + q * 8);
            acc[ft] = __builtin_amdgcn_mfma_f32_16x16x32_f16(afrag[kk], bfrag, acc[ft], 0, 0, 0);
        }
    }
    __syncthreads();   // all MFMA LDS reads done before aliasing as zsh

    // C layout: n(f) = ft*16 + (l&15), m(o) = w*16 + q*4 + r  -> zsh[o][f], stride 132
    #pragma unroll
    for (int ft = 0; ft < 8; ++ft) {
        #pragma unroll
        for (int r = 0; r < 4; ++r)
            zsh[(w * 16 + q * 4 + r) * 132 + ft * 16 + c16] = acc[ft][r];
    }
    __syncthreads();

    // ---- Entmax-1.5: lane owns row o = w*16 + (l>>2), f in [32s, 32s+32) ----
    // Root-finder: f(tau) = sum ReLU(z-tau)^2 - 1 is convex piecewise-quadratic,
    // decreasing. f(m-1) >= 0 always (max element contributes exactly 1), so the
    // reference's f_lo pass/sign-product is equivalent to testing f_m >= 0.
    // Plan: NBIS fp16-packed bisections (pk max/sub + v_dot2_f32_f16),
    // 2 fp16 Newton steps, 2 fp32 Newton polish. Worst-case tau err ~1e-5.
    const int row = l >> 2, s = l & 3;
    const int o = w * 16 + row;
    float zz[32];
    #pragma unroll
    for (int j = 0; j < 8; ++j) {
        floatx4 v = *(const floatx4*)(zsh + o * 132 + s * 32 + j * 4);
        zz[4 * j + 0] = v[0]; zz[4 * j + 1] = v[1];
        zz[4 * j + 2] = v[2]; zz[4 * j + 3] = v[3];
    }
    // max, 4 independent chains for ILP
    float m0 = zz[0], m1 = zz[1], m2 = zz[2], m3 = zz[3];
    #pragma unroll
    for (int j = 4; j < 32; j += 4) {
        m0 = fmaxf(m0, zz[j + 0]); m1 = fmaxf(m1, zz[j + 1]);
        m2 = fmaxf(m2, zz[j + 2]); m3 = fmaxf(m3, zz[j + 3]);
    }
    float m = fmaxf(fmaxf(m0, m1), fmaxf(m2, m3));
    m = fmaxf(m, __shfl_xor(m, 1));
    m = fmaxf(m, __shfl_xor(m, 2));

    float tau = m - 1.0f;
    float dm  = 0.9116116523516816f;        // 1 - (1/128)^0.5

#if HAS_FDOT2
    fp16x2 zh[16];
    #pragma unroll
    for (int j = 0; j < 16; ++j)
        zh[j] = __builtin_amdgcn_cvt_pkrtz(zz[2 * j], zz[2 * j + 1]);
    const fp16x2 hzero = { (__fp16)0.f, (__fp16)0.f };
    const fp16x2 hone  = { (__fp16)1.f, (__fp16)1.f };

    #pragma unroll
    for (int it = 0; it < NBIS; ++it) {
        dm *= 0.5f;
        float tm = tau + dm;
        fp16x2 t2 = __builtin_amdgcn_cvt_pkrtz(tm, tm);
        float sa = 0.f, sb = 0.f;
        #pragma unroll
        for (int j = 0; j < 16; j += 2) {
            fp16x2 d0 = __builtin_elementwise_max(zh[j]     - t2, hzero);
            fp16x2 d1 = __builtin_elementwise_max(zh[j + 1] - t2, hzero);
            sa = __builtin_amdgcn_fdot2(d0, d0, sa, false);
            sb = __builtin_amdgcn_fdot2(d1, d1, sb, false);
        }
        float sm = sa + sb;
        sm += __shfl_xor(sm, 1); sm += __shfl_xor(sm, 2);
        tau = (sm >= 1.0f) ? tm : tau;      // f_lo >= 0 -> sign test vs 1
    }
    // 2 fp16 Newton steps (monotone for convex f; Sum d >= ~1 so f' <= -2)
    #pragma unroll
    for (int it = 0; it < 2; ++it) {
        fp16x2 t2 = __builtin_amdgcn_cvt_pkrtz(tau, tau);
        float s2a = 0.f, s2b = 0.f, s1a = 0.f, s1b = 0.f;
        #pragma unroll
        for (int j = 0; j < 16; j += 2) {
            fp16x2 d0 = __builtin_elementwise_max(zh[j]     - t2, hzero);
            fp16x2 d1 = __builtin_elementwise_max(zh[j + 1] - t2, hzero);
            s2a = __builtin_amdgcn_fdot2(d0, d0, s2a, false);
            s2b = __builtin_amdgcn_fdot2(d1, d1, s2b, false);
            s1a = __builtin_amdgcn_fdot2(d0, hone, s1a, false);
            s1b = __builtin_amdgcn_fdot2(d1, hone, s1b, false);
        }
        float s2 = s2a + s2b, s1 = s1a + s1b;
        s2 += __shfl_xor(s2, 1); s2 += __shfl_xor(s2, 2);
        s1 += __shfl_xor(s1, 1); s1 += __shfl_xor(s1, 2);
        tau += (s2 - 1.0f) * frcp(fmaxf(s1 + s1, 1e-6f));
    }
#else
    // fallback: fp32 bisection (NBIS+4) + 1 extra fp32 Newton below
    #pragma unroll
    for (int it = 0; it < NBIS + 4; ++it) {
        dm *= 0.5f;
        float tm = tau + dm;
        float sa = 0.f, sb = 0.f;
        #pragma unroll
        for (int j = 0; j < 32; j += 2) {
            float d0 = fmaxf(zz[j] - tm, 0.f);
            float d1 = fmaxf(zz[j + 1] - tm, 0.f);
            sa = fmaf(d0, d0, sa); sb = fmaf(d1, d1, sb);
        }
        float sm = sa + sb;
        sm += __shfl_xor(sm, 1); sm += __shfl_xor(sm, 2);
        tau = (sm >= 1.0f) ? tm : tau;
    }
    {
        float s2a = 0.f, s2b = 0.f, s1a = 0.f, s1b = 0.f;
        #pragma unroll
        for (int j = 0; j < 32; j += 2) {
            float d0 = fmaxf(zz[j] - tau, 0.f);
            float d1 = fmaxf(zz[j + 1] - tau, 0.f);
            s2a = fmaf(d0, d0, s2a); s2b = fmaf(d1, d1, s2b);
            s1a += d0; s1b += d1;
        }
        float s2 = s2a + s2b, s1 = s1a + s1b;
        s2 += __shfl_xor(s2, 1); s2 += __shfl_xor(s2, 2);
        s1 += __shfl_xor(s1, 1); s1 += __shfl_xor(s1, 2);
        tau += (s2 - 1.0f) * frcp(fmaxf(s1 + s1, 1e-6f));
    }
#endif
    // final fp32 Newton polish (removes fp16 root bias; err -> ~1e-5)
    {
        float s2a = 0.f, s2b = 0.f, s1a = 0.f, s1b = 0.f;
        #pragma unroll
        for (int j = 0; j < 32; j += 2) {
            float d0 = fmaxf(zz[j] - tau, 0.f);
            float d1 = fmaxf(zz[j + 1] - tau, 0.f);
            s2a = fmaf(d0, d0, s2a); s2b = fmaf(d1, d1, s2b);
            s1a += d0; s1b += d1;
        }
        float s2 = s2a + s2b, s1 = s1a + s1b;
        s2 += __shfl_xor(s2, 1); s2 += __shfl_xor(s2, 2);
        s1 += __shfl_xor(s1, 1); s1 += __shfl_xor(s1, 2);
        tau += (s2 - 1.0f) * frcp(fmaxf(s1 + s1, 1e-6f));
    }

    // final p, normalization, scale by values
    float ps0 = 0.f, ps1 = 0.f;
    #pragma unroll
    for (int j = 0; j < 32; j += 2) {
        float d0 = fmaxf(zz[j] - tau, 0.f);
        float d1 = fmaxf(zz[j + 1] - tau, 0.f);
        float p0 = d0 * d0, p1 = d1 * d1;
        zz[j] = p0; zz[j + 1] = p1;
        ps0 += p0; ps1 += p1;
    }
    float ps = ps0 + ps1;
    ps += __shfl_xor(ps, 1); ps += __shfl_xor(ps, 2);
    const float inv = 1.0f / ps;

    const float* vrow = values + ((k * 64 + o) * 128 + s * 32);
    float* orow = out + ((((size_t)b * 8 + k) * 64 + o) * 128 + s * 32);
    #pragma unroll
    for (int j = 0; j < 8; ++j) {
        floatx4 vv = *(const floatx4*)(vrow + 4 * j);
        floatx4 g;
        g[0] = zz[4 * j + 0] * inv * vv[0];
        g[1] = zz[4 * j + 1] * inv * vv[1];
        g[2] = zz[4 * j + 2] * inv * vv[2];
        g[3] = zz[4 * j + 3] * inv * vv[3];
        *(floatx4*)(orow + 4 * j) = g;
    }
}

extern "C" void kernel_launch(void* const* d_in, const int* in_sizes, int n_in,
                              void* d_out, int out_size, void* d_ws, size_t ws_size,
                              hipStream_t stream) {
    const float* xg     = (const float*)d_in[0];   // [2048,128,128]
    const float* bw     = (const float*)d_in[1];   // [8,128,64]
    const float* qm     = (const float*)d_in[2];   // [8,64,64]
    const float* values = (const float*)d_in[3];   // [8,64,128]
    float* out = (float*)d_out;                    // [2048,8,64,128]
    _Float16* W2h = (_Float16*)d_ws;               // 65536 halves = 128 KB

    w2_kernel<<<64, 256, 0, stream>>>(bw, qm, W2h);
    satt_kernel<<<16384, 256, 0, stream>>>(xg, W2h, values, out);
}